// Round 8
// baseline (568.776 us; speedup 1.0000x reference)
//
#include <hip/hip_runtime.h>
#include <hip/hip_bf16.h>
#include <math.h>

#define N_NODES 8192
#define FEAT 512
#define NEGV -9e15f
#define VHPT_W 8704

typedef __attribute__((ext_vector_type(8))) short short8;
typedef __attribute__((ext_vector_type(4))) float floatx4;

// ---- workspace layout (bytes) ----
#define OFF_ABITS 0UL          // u64 adjbits [8192][128] (adj>0 bit-packed)
#define OFF_VHP   16777216UL   // bf16 vhp [8704][512] (padded-pos row-major)
#define OFF_KHP   33554432UL   // bf16 [8320][512]
#define OFF_VHPT  42074112UL   // bf16 [512][8704]  (padded-position columns)
#define OFF_MASK  50987008UL   // u64 [8192][128]; head reused early for cw (f64[1024])
#define OFF_S     59375616UL   // bf16 S, cap 25165824 elems; head reused early for Ab/W*T
#define OFF_PERM  109707264UL
#define OFF_BUCK  109772800UL
#define OFF_META  109805568UL  // ints: [0..4]=boff [5..8]=padded [9..13]=soff(+tot) [14..18]=poff
#define OFF_CMEAN 109806592UL
#define OFF_ROWI  109841408UL  // f32 [8192] row sum of stored P~ (exp(S), masked->0)
#define OFF_IPERM 109874176UL  // int [8192] inverse permutation
#define WS_NEEDED 109906944UL
#define CAP_S     25165824L

// aliased (early-lifetime) buffers inside the S region:
#define OFF_AB    (OFF_S)                 // bf16 [8192][512] input, bf16
#define OFF_WKT   (OFF_S + 16777216UL)    // bf16 [512][512] kW transposed
#define OFF_WVT   (OFF_S + 17825792UL)    // bf16 [512][512] vW transposed
#define OFF_CW    (OFF_MASK)              // f64 [512][2] (dead before maskpack2)

static __device__ __forceinline__ unsigned short f2bf_bits(float x) {
  __hip_bfloat16 h = __float2bfloat16(x);
  unsigned short u;
  __builtin_memcpy(&u, &h, 2);
  return u;
}
static __device__ __forceinline__ float bf_bits2f(unsigned short u) {
  __hip_bfloat16 h;
  __builtin_memcpy(&h, &u, 2);
  return __bfloat162float(h);
}

// Async 16B/lane global->LDS copy (global_load_lds_dwordx4). LDS side must be
// wave-uniform base + lane*16 — all call sites below satisfy this.
static __device__ __forceinline__ void async_copy16(const void* gptr,
                                                    void* lptr) {
  __builtin_amdgcn_global_load_lds(
      (const __attribute__((address_space(1))) unsigned int*)gptr,
      (__attribute__((address_space(3))) unsigned int*)lptr, 16, 0, 0);
}

// ---------------------------------------------------------------------------
// adjbits[i][w] bit l = (adj[i][w*64+l] > 0). Pure coalesced stream + ballot.
// Launched FIRST: its 268 MB adj read does the L3 eviction before any
// producer->consumer buffer is cached, and later passes touch only 8 MB.
// ---------------------------------------------------------------------------
__global__ __launch_bounds__(256) void adjbits_kernel(
    const int* __restrict__ adj, unsigned long long* __restrict__ adjbits) {
  const int i = blockIdx.x;
  const int t = threadIdx.x;
  const int lane = t & 63, w = t >> 6;
  const int* arow = adj + (long)i * N_NODES;
  unsigned long long* brow = adjbits + (long)i * 128;
#pragma unroll
  for (int s = 0; s < 32; s++) {
    int col = w * 64 + lane + s * 256;  // word (s*4+w) covers cols [.., +64)
    int pred = arow[col] > 0;
    unsigned long long mword = __ballot(pred);
    if (lane == 0) brow[s * 4 + w] = mword;
  }
}

// ---------------------------------------------------------------------------
// maskbits[g][jj] = bit of adjbits[perm[g]] at column perm[boff_b+jj].
// Reads only the 8 MB L3-hot bit matrix; 1 KB LDS stage per row.
// ---------------------------------------------------------------------------
__global__ __launch_bounds__(256) void maskpack2_kernel(
    const unsigned long long* __restrict__ adjbits,
    const int* __restrict__ perm, const int* __restrict__ meta,
    unsigned long long* __restrict__ maskbits) {
  __shared__ unsigned long long bits[128];
  const int g = blockIdx.x;
  const int t = threadIdx.x;
  const int b = (g >= meta[1]) + (g >= meta[2]) + (g >= meta[3]);
  const int boff = meta[b];
  const int n_b = meta[b + 1] - boff;
  const int padded = meta[5 + b];
  const int i = perm[g];
  if (t < 128) bits[t] = adjbits[(long)i * 128 + t];
  __syncthreads();
  const int lane = t & 63, w = t >> 6;
  for (int jj0 = w * 64; jj0 < padded; jj0 += 256) {
    int jj = jj0 + lane;
    int pred = 0;
    if (jj < n_b) {
      int p = perm[boff + jj];
      pred = (int)((bits[p >> 6] >> (p & 63)) & 1ULL);
    }
    unsigned long long mword = __ballot(pred);
    if (lane == 0) maskbits[(long)g * 128 + (jj0 >> 6)] = mword;
  }
}

// ---------------------------------------------------------------------------
// input f32 -> bf16
// ---------------------------------------------------------------------------
__global__ __launch_bounds__(256) void convert_input(
    const float* __restrict__ A, __hip_bfloat16* __restrict__ Ab) {
  const long idx = ((long)blockIdx.x * 256 + threadIdx.x) * 8;
  const float4 v0 = *(const float4*)&A[idx];
  const float4 v1 = *(const float4*)&A[idx + 4];
  const float vv[8] = {v0.x, v0.y, v0.z, v0.w, v1.x, v1.y, v1.z, v1.w};
  union { short8 s; unsigned short u[8]; } o;
#pragma unroll
  for (int e = 0; e < 8; e++) o.u[e] = f2bf_bits(vv[e]);
  *(short8*)&Ab[idx] = o.s;
}

// ---------------------------------------------------------------------------
// W[k][n] f32 -> transposed bf16: WT[n][k]. z=0: kW, z=1: vW.
// ---------------------------------------------------------------------------
__global__ __launch_bounds__(256) void convert_w(
    const float* __restrict__ kW, const float* __restrict__ vW,
    __hip_bfloat16* __restrict__ WkT, __hip_bfloat16* __restrict__ WvT) {
  __shared__ float tile[64][65];
  const int z = blockIdx.z;
  const float* __restrict__ W = z ? vW : kW;
  __hip_bfloat16* __restrict__ T = z ? WvT : WkT;
  const int k0 = blockIdx.x * 64, n0 = blockIdx.y * 64;
  const int t = threadIdx.x;
#pragma unroll
  for (int s = 0; s < 16; s++) {
    int idx = t + s * 256;
    int r = idx >> 6, c = idx & 63;
    tile[r][c] = W[(long)(k0 + r) * FEAT + n0 + c];
  }
  __syncthreads();
#pragma unroll
  for (int s = 0; s < 16; s++) {
    int idx = t + s * 256;
    int a = idx >> 6, b = idx & 63;
    unsigned short h = f2bf_bits(tile[b][a]);
    __builtin_memcpy(&T[(long)(n0 + a) * FEAT + k0 + b], &h, 2);
  }
}

// ---------------------------------------------------------------------------
// kh/vh = A@W, plain bf16 MFMA. BK=64 dbuf, 32 MFMAs per barrier, 8 K-steps.
// Unified epilogue: acc -> Ct LDS tile -> coalesced 16B row stores, rows
// scattered to:
//   z=0: khp[iperm[r]]           (sorted order, feeds s_gemm)
//   z=1: vhp[pos(iperm[r])]      (padded-position order, feeds transpose)
// ---------------------------------------------------------------------------
__global__ __launch_bounds__(256) void mfma_dual(
    const __hip_bfloat16* __restrict__ Ab, const __hip_bfloat16* __restrict__ WkT,
    const __hip_bfloat16* __restrict__ WvT, const int* __restrict__ iperm,
    const int* __restrict__ meta, __hip_bfloat16* __restrict__ khp,
    __hip_bfloat16* __restrict__ vhp) {
  const int z = blockIdx.z;
  const __hip_bfloat16* __restrict__ WT = z ? WvT : WkT;
  const int ti = blockIdx.x, tj = blockIdx.y;
  // 64 KB union: As/Ws each [2 dbuf][2 panels][4096]; Ct[128][136] epilogue.
  __shared__ __align__(16) __hip_bfloat16 smem[32768];
  __hip_bfloat16* As = smem;            // [2][2][4096]
  __hip_bfloat16* Ws = smem + 16384;    // [2][2][4096]
  const int t = threadIdx.x;
  const int lane = t & 63, w = t >> 6;
  const int wm = (w >> 1) * 64, wn = (w & 1) * 64;
  const int quad = lane >> 4, ln = lane & 15;
  const int qr = quad * 8;
  floatx4 acc[4][4];
#pragma unroll
  for (int mi = 0; mi < 4; mi++)
#pragma unroll
    for (int ni = 0; ni < 4; ni++) acc[mi][ni] = (floatx4)0.f;

  auto STAGE = [&](int st, int buf) {
    const int k0 = st * 64;
#pragma unroll
    for (int p = 0; p < 2; p++)
#pragma unroll
      for (int s = 0; s < 2; s++) {
        int c = t + s * 256;
        int row = c >> 2, off8 = (c & 3) * 8;
        int lo = buf * 8192 + p * 4096 + row * 32 + off8;
        async_copy16(&Ab[(long)(ti * 128 + row) * FEAT + k0 + p * 32 + off8],
                     &As[lo]);
        async_copy16(&WT[(long)(tj * 128 + row) * FEAT + k0 + p * 32 + off8],
                     &Ws[lo]);
      }
  };
  STAGE(0, 0);
  __syncthreads();
  for (int st = 0; st < 8; st++) {
    const int buf = st & 1;
    if (st < 7) STAGE(st + 1, buf ^ 1);
#pragma unroll
    for (int p = 0; p < 2; p++) {
      short8 af[4], bfr[4];
#pragma unroll
      for (int mi = 0; mi < 4; mi++)
        af[mi] = *(const short8*)&As[buf * 8192 + p * 4096 +
                                     (wm + mi * 16 + ln) * 32 + qr];
#pragma unroll
      for (int ni = 0; ni < 4; ni++)
        bfr[ni] = *(const short8*)&Ws[buf * 8192 + p * 4096 +
                                      (wn + ni * 16 + ln) * 32 + qr];
#pragma unroll
      for (int mi = 0; mi < 4; mi++)
#pragma unroll
        for (int ni = 0; ni < 4; ni++)
          acc[mi][ni] = __builtin_amdgcn_mfma_f32_16x16x32_bf16(
              af[mi], bfr[ni], acc[mi][ni], 0, 0, 0);
    }
    __syncthreads();
  }
  // unified epilogue: loop-end barrier already drained LDS reads
  __hip_bfloat16* Ct = smem;  // [128][136]
#pragma unroll
  for (int mi = 0; mi < 4; mi++)
#pragma unroll
    for (int ni = 0; ni < 4; ni++) {
      int col = wn + ni * 16 + ln;
#pragma unroll
      for (int reg = 0; reg < 4; reg++) {
        int row = wm + mi * 16 + quad * 4 + reg;
        Ct[row * 136 + col] = __float2bfloat16(acc[mi][ni][reg]);
      }
    }
  __syncthreads();
  __hip_bfloat16* __restrict__ dst = z ? vhp : khp;
#pragma unroll
  for (int i = 0; i < 8; i++) {
    int idx = t + i * 256;
    int rl = idx >> 4, c8 = (idx & 15) * 8;
    int g = iperm[ti * 128 + rl];
    long drow = g;
    if (z) {
      int bb = (g >= meta[1]) + (g >= meta[2]) + (g >= meta[3]);
      drow = meta[14 + bb] + g - meta[bb];
    }
    *(short8*)&dst[drow * FEAT + tj * 128 + c8] =
        *(const short8*)&Ct[rl * 136 + c8];
  }
}

// ---------------------------------------------------------------------------
// cw[f][b] = sum_h kW[f][h] * rot[h][b]  (fp64)
// ---------------------------------------------------------------------------
__global__ __launch_bounds__(64) void cw_kernel(
    const float* __restrict__ kW, const float* __restrict__ rot,
    double* __restrict__ cw) {
  const int f = blockIdx.x;
  const int lane = threadIdx.x;
  double r0 = 0.0, r1 = 0.0;
  for (int h = lane; h < FEAT; h += 64) {
    double a = (double)kW[(long)f * FEAT + h];
    r0 += a * (double)rot[2 * h];
    r1 += a * (double)rot[2 * h + 1];
  }
#pragma unroll
  for (int off = 32; off > 0; off >>= 1) {
    r0 += __shfl_down(r0, off);
    r1 += __shfl_down(r1, off);
  }
  if (lane == 0) {
    cw[2 * f] = r0;
    cw[2 * f + 1] = r1;
  }
}

// ---------------------------------------------------------------------------
// buckets from EXACT inputs: rv = input @ cw in fp64; argmax([r0,r1,-r0,-r1])
// ---------------------------------------------------------------------------
__global__ __launch_bounds__(64) void rv_bucket_kernel(
    const float* __restrict__ input, const double* __restrict__ cw,
    int* __restrict__ buckets) {
  const int i = blockIdx.x;
  const int lane = threadIdx.x;
  double r0 = 0.0, r1 = 0.0;
  for (int f = lane; f < FEAT; f += 64) {
    double a = (double)input[(long)i * FEAT + f];
    r0 += a * cw[2 * f];
    r1 += a * cw[2 * f + 1];
  }
#pragma unroll
  for (int off = 32; off > 0; off >>= 1) {
    r0 += __shfl_down(r0, off);
    r1 += __shfl_down(r1, off);
  }
  if (lane == 0) {
    int b = 0;
    double best = r0;
    if (r1 > best)  { best = r1;  b = 1; }
    if (-r0 > best) { best = -r0; b = 2; }
    if (-r1 > best) { best = -r1; b = 3; }
    buckets[i] = b;
  }
}

// ---------------------------------------------------------------------------
// Stable counting sort by bucket (1 block, parallel Hillis-Steele scan).
// Emits perm AND inverse perm. Also zeroes cmean and rowsum.
// ---------------------------------------------------------------------------
__global__ __launch_bounds__(256) void sort_kernel(
    const int* __restrict__ buckets, int* __restrict__ perm,
    int* __restrict__ iperm, int* __restrict__ meta,
    float* __restrict__ cmean, float* __restrict__ rowsum) {
  __shared__ int lc[4][256];
  __shared__ int sc[4][256];
  __shared__ int boff_sh[5];
  const int t = threadIdx.x;
  cmean[t] = 0.f;
  cmean[t + 256] = 0.f;
  for (int k = t; k < N_NODES; k += 256) rowsum[k] = 0.f;
  const int base = t * 32;
  int c0 = 0, c1 = 0, c2 = 0, c3 = 0;
  for (int k = 0; k < 32; k++) {
    int b = buckets[base + k];
    c0 += (b == 0); c1 += (b == 1); c2 += (b == 2); c3 += (b == 3);
  }
  lc[0][t] = c0; lc[1][t] = c1; lc[2][t] = c2; lc[3][t] = c3;
  sc[0][t] = c0; sc[1][t] = c1; sc[2][t] = c2; sc[3][t] = c3;
  __syncthreads();
  for (int off = 1; off < 256; off <<= 1) {
    int a0 = (t >= off) ? sc[0][t - off] : 0;
    int a1 = (t >= off) ? sc[1][t - off] : 0;
    int a2 = (t >= off) ? sc[2][t - off] : 0;
    int a3 = (t >= off) ? sc[3][t - off] : 0;
    __syncthreads();
    sc[0][t] += a0; sc[1][t] += a1; sc[2][t] += a2; sc[3][t] += a3;
    __syncthreads();
  }
  if (t == 0) {
    int boff[5];
    boff[0] = 0;
    for (int b = 0; b < 4; b++) boff[b + 1] = boff[b] + sc[b][255];
    for (int b = 0; b < 5; b++) { meta[b] = boff[b]; boff_sh[b] = boff[b]; }
    long so = 0;
    int po = 0;
    for (int b = 0; b < 4; b++) {
      int tot = boff[b + 1] - boff[b];
      int pad = ((tot + 127) >> 7) << 7;
      meta[5 + b] = pad;
      meta[9 + b] = (int)so;
      meta[14 + b] = po;
      so += (long)pad * pad;
      po += pad;
    }
    meta[13] = (int)so;
    meta[18] = po;
    if (so > CAP_S)
      for (int b = 0; b < 4; b++) meta[5 + b] = 0;
  }
  __syncthreads();
  int s0 = boff_sh[0] + sc[0][t] - lc[0][t];
  int s1 = boff_sh[1] + sc[1][t] - lc[1][t];
  int s2 = boff_sh[2] + sc[2][t] - lc[2][t];
  int s3 = boff_sh[3] + sc[3][t] - lc[3][t];
  for (int k = 0; k < 32; k++) {
    int i = base + k;
    int b = buckets[i];
    int pos = (b == 0) ? s0++ : ((b == 1) ? s1++ : ((b == 2) ? s2++ : s3++));
    perm[pos] = i;
    iperm[i] = pos;
  }
}

// ---------------------------------------------------------------------------
// Plain bf16 transpose vhp[pos][f] -> vhpT[f][pos], fused cmean column sums.
// Pads are zero (vhp memset upfront; mfma_dual writes only real nodes).
// ---------------------------------------------------------------------------
__global__ __launch_bounds__(256) void transpose_vhpT_kernel(
    const __hip_bfloat16* __restrict__ vhp, __hip_bfloat16* __restrict__ vhpT,
    float* __restrict__ cmean) {
  __shared__ float tile[64][65];
  __shared__ float cred[4][64];
  const int g0 = blockIdx.x * 64;
  const int f0 = blockIdx.y * 64;
  const int t = threadIdx.x;
#pragma unroll
  for (int s = 0; s < 4; s++) {
    int idx = t + s * 256;              // 0..1023
    int r = idx >> 4, c4 = (idx & 15) * 4;
    ushort4 v = *(const ushort4*)&vhp[(long)(g0 + r) * FEAT + f0 + c4];
    tile[r][c4]     = bf_bits2f(v.x);
    tile[r][c4 + 1] = bf_bits2f(v.y);
    tile[r][c4 + 2] = bf_bits2f(v.z);
    tile[r][c4 + 3] = bf_bits2f(v.w);
  }
  __syncthreads();
  {
    const int c = t & 63, seg = t >> 6;
    float ps = 0.f;
#pragma unroll
    for (int rr = 0; rr < 16; rr++) ps += tile[seg * 16 + rr][c];
    cred[seg][c] = ps;
  }
  __syncthreads();
  if (t < 64)
    atomicAdd(&cmean[f0 + t],
              cred[0][t] + cred[1][t] + cred[2][t] + cred[3][t]);
#pragma unroll
  for (int s = 0; s < 2; s++) {
    int idx = t + s * 256;              // 0..511
    int fr = idx >> 3, gc8 = (idx & 7) * 8;
    union { short8 v; unsigned short u[8]; } pk;
#pragma unroll
    for (int e = 0; e < 8; e++) pk.u[e] = f2bf_bits(tile[gc8 + e][fr]);
    *(short8*)&vhpT[(long)(f0 + fr) * VHPT_W + g0 + gc8] = pk.v;
  }
}

// ---------------------------------------------------------------------------
// S tile = khp_b . khp_b^T (bf16 MFMA). Dbuf prefetch per 64-wide K-step.
// FUSED NO-MAX SOFTMAX NUMERATOR: epilogue stores P~ = bf16(exp(S/sqrt(H)))
// (masked -> 0) and accumulates f32 row sums via 16-lane shfl reduce + one
// atomicAdd per (row, tile). Scores bounded (~50 << 88) so f32 exp cannot
// overflow; exp(S)/sum == softmax exactly. Triangular grid ti <= tj; both
// orientations written from an LDS tile with coalesced 16B stores. Pad rows
// excluded from row-sum atomics.
// ---------------------------------------------------------------------------
__global__ __launch_bounds__(256) void s_gemm(
    const __hip_bfloat16* __restrict__ khp, const int* __restrict__ meta,
    const unsigned long long* __restrict__ maskbits,
    __hip_bfloat16* __restrict__ S, float* __restrict__ rowsum) {
  const int b = blockIdx.z;
  const int padded = meta[5 + b];
  const int T = padded >> 7;
  const int pairs = (T * (T + 1)) >> 1;
  int L = blockIdx.x;
  if (L >= pairs) return;
  int ti = 0;
  while (L >= T - ti) { L -= T - ti; ti++; }
  const int tj = ti + L;
  const int boff = meta[b];
  const int n_b = meta[b + 1] - boff;
  const long soff = meta[9 + b];
  // 64 KB: As/Bs each [2 dbuf][2 panels][4096]; Ct[128][136] epilogue.
  __shared__ __align__(16) __hip_bfloat16 smem[32768];
  __hip_bfloat16* As = smem;            // [2][2][4096]
  __hip_bfloat16* Bs = smem + 16384;    // [2][2][4096]
  const int t = threadIdx.x;
  const int lane = t & 63, w = t >> 6;
  const int wm = (w >> 1) * 64, wn = (w & 1) * 64;
  const int quad = lane >> 4, ln = lane & 15;
  const int qr = quad * 8;
  floatx4 acc[4][4];
#pragma unroll
  for (int mi = 0; mi < 4; mi++)
#pragma unroll
    for (int ni = 0; ni < 4; ni++) acc[mi][ni] = (floatx4)0.f;
  const long a_g0 = boff + ti * 128;
  const long b_g0 = boff + tj * 128;

  auto STAGE = [&](int st, int buf) {
    const int k0 = st * 64;
#pragma unroll
    for (int p = 0; p < 2; p++)
#pragma unroll
      for (int s = 0; s < 2; s++) {
        int c = t + s * 256;
        int row = c >> 2, off8 = (c & 3) * 8;
        int lo = buf * 8192 + p * 4096 + row * 32 + off8;
        async_copy16(&khp[(a_g0 + row) * FEAT + k0 + p * 32 + off8], &As[lo]);
        async_copy16(&khp[(b_g0 + row) * FEAT + k0 + p * 32 + off8], &Bs[lo]);
      }
  };
  STAGE(0, 0);
  __syncthreads();
  for (int st = 0; st < 8; st++) {
    const int buf = st & 1;
    if (st < 7) STAGE(st + 1, buf ^ 1);
#pragma unroll
    for (int p = 0; p < 2; p++) {
      short8 af[4], bfr[4];
#pragma unroll
      for (int mi = 0; mi < 4; mi++)
        af[mi] = *(const short8*)&As[buf * 8192 + p * 4096 +
                                     (wm + mi * 16 + ln) * 32 + qr];
#pragma unroll
      for (int ni = 0; ni < 4; ni++)
        bfr[ni] = *(const short8*)&Bs[buf * 8192 + p * 4096 +
                                      (wn + ni * 16 + ln) * 32 + qr];
#pragma unroll
      for (int mi = 0; mi < 4; mi++)
#pragma unroll
        for (int ni = 0; ni < 4; ni++)
          acc[mi][ni] = __builtin_amdgcn_mfma_f32_16x16x32_bf16(
              af[mi], bfr[ni], acc[mi][ni], 0, 0, 0);
    }
    __syncthreads();
  }
  // ---- epilogue: P~ = bf16(exp(acc*scale)) -> LDS tile (unmasked) ----
  const float scale = 0.04419417382415922f;  // 1/sqrt(512)
  __hip_bfloat16* Ct = smem;  // [128][136]
#pragma unroll
  for (int mi = 0; mi < 4; mi++)
#pragma unroll
    for (int ni = 0; ni < 4; ni++) {
      int col = wn + ni * 16 + ln;
#pragma unroll
      for (int reg = 0; reg < 4; reg++) {
        int row = wm + mi * 16 + quad * 4 + reg;
        Ct[row * 136 + col] =
            __float2bfloat16(__expf(acc[mi][ni][reg] * scale));
      }
    }
  __syncthreads();
  // normal orientation: coalesced 16B stores of rows of the ti-block
#pragma unroll
  for (int i = 0; i < 8; i++) {
    int idx = t + i * 256;
    int rl = idx >> 4, c8 = (idx & 15) * 8;
    int rg = ti * 128 + rl;
    int cg = tj * 128 + c8;
    union { short8 v; unsigned short u[8]; } pk;
    pk.v = *(const short8*)&Ct[rl * 136 + c8];
    unsigned long long wbits = maskbits[(long)(boff + rg) * 128 + (cg >> 6)];
    float ps = 0.f;
#pragma unroll
    for (int e = 0; e < 8; e++) {
      if (!((wbits >> ((cg & 63) + e)) & 1ULL)) pk.u[e] = 0;
      ps += bf_bits2f(pk.u[e]);
    }
    *(short8*)&S[soff + (long)rg * padded + cg] = pk.v;
    // per-row partial sum: 16 consecutive lanes share rg
#pragma unroll
    for (int off = 1; off < 16; off <<= 1) ps += __shfl_xor(ps, off);
    if (rg < n_b && (lane & 15) == 0)
      atomicAdd(&rowsum[boff + rg], ps);
  }
  // mirrored orientation (tj-block rows), skipped on diagonal
  if (ti != tj) {
#pragma unroll
    for (int i = 0; i < 8; i++) {
      int idx = t + i * 256;
      int cl = idx >> 4, r8 = (idx & 15) * 8;
      int rg = tj * 128 + cl;   // output row (column of the computed tile)
      int cg = ti * 128 + r8;   // output col base
      union { short8 v; unsigned short u[8]; } pk;
#pragma unroll
      for (int e = 0; e < 8; e++) {
        __hip_bfloat16 hv = Ct[(r8 + e) * 136 + cl];
        __builtin_memcpy(&pk.u[e], &hv, 2);
      }
      unsigned long long wbits = maskbits[(long)(boff + rg) * 128 + (cg >> 6)];
      float ps = 0.f;
#pragma unroll
      for (int e = 0; e < 8; e++) {
        if (!((wbits >> ((cg & 63) + e)) & 1ULL)) pk.u[e] = 0;
        ps += bf_bits2f(pk.u[e]);
      }
      *(short8*)&S[soff + (long)rg * padded + cg] = pk.v;
#pragma unroll
      for (int off = 1; off < 16; off <<= 1) ps += __shfl_xor(ps, off);
      if (rg < n_b && (lane & 15) == 0)
        atomicAdd(&rowsum[boff + rg], ps);
    }
  }
}

// ---------------------------------------------------------------------------
// O tile = P~ . vhp (pure bf16 GEMM), 64 rows x 128 features per block
// (round-6 shape: 528 blocks ~ 2/CU — cross-block overlap is the latency
// hider in this template; 128x128 @ 1/CU measured slower, round 7).
// Dbuf prefetch per 64-wide K-step. Epilogue: x (1/rowsum) + ELU +
// empty-row (rowsum==0) cmean fallback + scatter to out[perm[g]].
// ---------------------------------------------------------------------------
__global__ __launch_bounds__(256) void pv_gemm(
    const __hip_bfloat16* __restrict__ S, const __hip_bfloat16* __restrict__ vhpT,
    const int* __restrict__ meta, const int* __restrict__ perm,
    const float* __restrict__ cmean, const float* __restrict__ rowsum,
    float* __restrict__ out) {
  const int b = blockIdx.z;
  const int padded = meta[5 + b];
  const int ti = blockIdx.x;
  if (ti * 64 >= padded) return;
  const int boff = meta[b];
  const int n_b = meta[b + 1] - boff;
  const long soff = meta[9 + b];
  const int poff = meta[14 + b];
  const int f0 = blockIdx.y * 128;
  __shared__ __align__(16) __hip_bfloat16 As[2 * 2 * 2048];  // 16 KB
  __shared__ __align__(16) __hip_bfloat16 Bs[2 * 2 * 4096];  // 32 KB
  const int t = threadIdx.x;
  const int lane = t & 63, w = t >> 6;
  const int wm = (w >> 1) * 32, wn = (w & 1) * 64;
  const int quad = lane >> 4, ln = lane & 15;
  const int qr = quad * 8;
  floatx4 acc[2][4];
#pragma unroll
  for (int mi = 0; mi < 2; mi++)
#pragma unroll
    for (int ni = 0; ni < 4; ni++) acc[mi][ni] = (floatx4)0.f;
  const long r0 = (long)ti * 64;

  auto STAGE = [&](int st, int buf) {
    const int k0 = st * 64;
#pragma unroll
    for (int p = 0; p < 2; p++) {
      {
        int row = t >> 2, off8 = (t & 3) * 8;
        async_copy16(&S[soff + (r0 + row) * padded + k0 + p * 32 + off8],
                     &As[buf * 4096 + p * 2048 + row * 32 + off8]);
      }
#pragma unroll
      for (int s = 0; s < 2; s++) {
        int c = t + s * 256;
        int row = c >> 2, off8 = (c & 3) * 8;
        async_copy16(
            &vhpT[(long)(f0 + row) * VHPT_W + poff + k0 + p * 32 + off8],
            &Bs[buf * 8192 + p * 4096 + row * 32 + off8]);
      }
    }
  };
  const int NS = padded >> 6;
  STAGE(0, 0);
  __syncthreads();
  for (int st = 0; st < NS; st++) {
    const int buf = st & 1;
    if (st + 1 < NS) STAGE(st + 1, buf ^ 1);
#pragma unroll
    for (int p = 0; p < 2; p++) {
      short8 af[2], bfr[4];
#pragma unroll
      for (int mi = 0; mi < 2; mi++)
        af[mi] = *(const short8*)&As[buf * 4096 + p * 2048 +
                                     (wm + mi * 16 + ln) * 32 + qr];
#pragma unroll
      for (int ni = 0; ni < 4; ni++)
        bfr[ni] = *(const short8*)&Bs[buf * 8192 + p * 4096 +
                                      (wn + ni * 16 + ln) * 32 + qr];
#pragma unroll
      for (int mi = 0; mi < 2; mi++)
#pragma unroll
        for (int ni = 0; ni < 4; ni++)
          acc[mi][ni] = __builtin_amdgcn_mfma_f32_16x16x32_bf16(
              af[mi], bfr[ni], acc[mi][ni], 0, 0, 0);
    }
    __syncthreads();
  }
#pragma unroll
  for (int mi = 0; mi < 2; mi++) {
#pragma unroll
    for (int reg = 0; reg < 4; reg++) {
      int r = ti * 64 + wm + mi * 16 + quad * 4 + reg;
      if (r < n_b) {
        int g = boff + r;
        int node = perm[g];
        float rs = rowsum[g];
        int fl = (rs == 0.f);
        float inv = fl ? 0.f : 1.f / rs;
#pragma unroll
        for (int ni = 0; ni < 4; ni++) {
          int fc = f0 + wn + ni * 16 + ln;
          float v = fl ? cmean[fc] * (1.f / (float)N_NODES)
                       : acc[mi][ni][reg] * inv;
          v = v > 0.f ? v : expm1f(v);
          out[(long)node * FEAT + fc] = v;
        }
      }
    }
  }
}

// ===========================================================================
// Slow-path fallback (only if ws_size < WS_NEEDED): round-1 implementation.
// ===========================================================================
__global__ __launch_bounds__(256) void gemm_dual(
    const float* __restrict__ A, const float* __restrict__ Wk,
    const float* __restrict__ Wv, float* __restrict__ kh,
    float* __restrict__ vh) {
  __shared__ float As[32][33];
  __shared__ float Bk[32][33];
  __shared__ float Bv[32][33];
  const int tid = threadIdx.x;
  const int row0 = blockIdx.x * 32;
  const int col0 = blockIdx.y * 32;
  const int tx = tid & 15, ty = tid >> 4;
  float ck00 = 0.f, ck01 = 0.f, ck10 = 0.f, ck11 = 0.f;
  float cv00 = 0.f, cv01 = 0.f, cv10 = 0.f, cv11 = 0.f;
  for (int kt = 0; kt < FEAT; kt += 32) {
#pragma unroll
    for (int t = 0; t < 4; t++) {
      int e = tid + t * 256;
      int r = e >> 5, c = e & 31;
      As[r][c] = A[(long)(row0 + r) * FEAT + kt + c];
      Bk[r][c] = Wk[(long)(kt + r) * FEAT + col0 + c];
      Bv[r][c] = Wv[(long)(kt + r) * FEAT + col0 + c];
    }
    __syncthreads();
#pragma unroll
    for (int kk = 0; kk < 32; kk++) {
      float a0 = As[ty * 2][kk], a1 = As[ty * 2 + 1][kk];
      float bk0 = Bk[kk][tx * 2], bk1 = Bk[kk][tx * 2 + 1];
      float bv0 = Bv[kk][tx * 2], bv1 = Bv[kk][tx * 2 + 1];
      ck00 += a0 * bk0; ck01 += a0 * bk1;
      ck10 += a1 * bk0; ck11 += a1 * bk1;
      cv00 += a0 * bv0; cv01 += a0 * bv1;
      cv10 += a1 * bv0; cv11 += a1 * bv1;
    }
    __syncthreads();
  }
  const int r0 = row0 + ty * 2, c0 = col0 + tx * 2;
  kh[(long)r0 * FEAT + c0] = ck00;       kh[(long)r0 * FEAT + c0 + 1] = ck01;
  kh[(long)(r0 + 1) * FEAT + c0] = ck10; kh[(long)(r0 + 1) * FEAT + c0 + 1] = ck11;
  vh[(long)r0 * FEAT + c0] = cv00;       vh[(long)r0 * FEAT + c0 + 1] = cv01;
  vh[(long)(r0 + 1) * FEAT + c0] = cv10; vh[(long)(r0 + 1) * FEAT + c0 + 1] = cv11;
}

__global__ __launch_bounds__(64) void bucket_kernel(
    const float* __restrict__ kh, const float* __restrict__ rot,
    int* __restrict__ buckets) {
  const int i = blockIdx.x;
  const int lane = threadIdx.x;
  double r0 = 0.0, r1 = 0.0;
  for (int h = lane; h < FEAT; h += 64) {
    double a = (double)kh[(long)i * FEAT + h];
    r0 += a * (double)rot[2 * h];
    r1 += a * (double)rot[2 * h + 1];
  }
#pragma unroll
  for (int off = 32; off > 0; off >>= 1) {
    r0 += __shfl_down(r0, off);
    r1 += __shfl_down(r1, off);
  }
  if (lane == 0) {
    int b = 0;
    double best = r0;
    if (r1 > best)  { best = r1;  b = 1; }
    if (-r0 > best) { best = -r0; b = 2; }
    if (-r1 > best) { best = -r1; b = 3; }
    buckets[i] = b;
  }
}

__global__ __launch_bounds__(256) void attn_kernel(
    const float* __restrict__ kh, const float* __restrict__ vh,
    const int* __restrict__ adj, const int* __restrict__ buckets,
    float* __restrict__ out) {
  __shared__ float khi[FEAT];
  __shared__ float pbuf[N_NODES];
  __shared__ unsigned short jlist[N_NODES];
  __shared__ int cnt_sh;
  __shared__ float red[256];
  const int i = blockIdx.x;
  const int tid = threadIdx.x;
  if (tid == 0) cnt_sh = 0;
  for (int k = tid; k < FEAT; k += 256) khi[k] = kh[(long)i * FEAT + k];
  const int mybucket = buckets[i];
  __syncthreads();
  const int* adjrow = adj + (long)i * N_NODES;
  for (int j = tid; j < N_NODES; j += 256) {
    if (adjrow[j] > 0 && buckets[j] == mybucket) {
      int idx = atomicAdd(&cnt_sh, 1);
      jlist[idx] = (unsigned short)j;
    }
  }
  __syncthreads();
  const int cnt = cnt_sh;
  float mloc = -INFINITY;
  for (int idx = tid; idx < cnt; idx += 256) {
    int j = jlist[idx];
    const float4* kj = (const float4*)(kh + (long)j * FEAT);
    const float4* ki = (const float4*)khi;
    float acc = 0.f;
#pragma unroll 8
    for (int k = 0; k < FEAT / 4; k++) {
      float4 a = ki[k];
      float4 b = kj[k];
      acc += a.x * b.x + a.y * b.y + a.z * b.z + a.w * b.w;
    }
    float s = acc * 0.04419417382415922f;
    pbuf[idx] = s;
    mloc = fmaxf(mloc, s);
  }
  red[tid] = mloc;
  __syncthreads();
#pragma unroll
  for (int off = 128; off > 0; off >>= 1) {
    if (tid < off) red[tid] = fmaxf(red[tid], red[tid + off]);
    __syncthreads();
  }
  const float m = red[0];
  __syncthreads();
  float lloc = 0.f;
  for (int idx = tid; idx < cnt; idx += 256) {
    float p = expf(pbuf[idx] - m);
    pbuf[idx] = p;
    lloc += p;
  }
  red[tid] = lloc;
  __syncthreads();
#pragma unroll
  for (int off = 128; off > 0; off >>= 1) {
    if (tid < off) red[tid] += red[tid + off];
    __syncthreads();
  }
  const float l = red[0];
  __syncthreads();
  const int f = 2 * tid;
  float acc0 = 0.f, acc1 = 0.f;
  if (cnt > 0) {
#pragma unroll 4
    for (int idx = 0; idx < cnt; idx++) {
      int j = jlist[idx];
      float p = pbuf[idx];
      float2 v = *(const float2*)(vh + (long)j * FEAT + f);
      acc0 += p * v.x;
      acc1 += p * v.y;
    }
    float invl = 1.f / l;
    acc0 *= invl;
    acc1 *= invl;
  } else {
    for (int j = 0; j < N_NODES; j++) {
      float2 v = *(const float2*)(vh + (long)j * FEAT + f);
      acc0 += v.x;
      acc1 += v.y;
    }
    acc0 *= (1.f / (float)N_NODES);
    acc1 *= (1.f / (float)N_NODES);
  }
  acc0 = acc0 > 0.f ? acc0 : expm1f(acc0);
  acc1 = acc1 > 0.f ? acc1 : expm1f(acc1);
  *(float2*)(out + (long)i * FEAT + f) = make_float2(acc0, acc1);
}

extern "C" void kernel_launch(void* const* d_in, const int* in_sizes, int n_in,
                              void* d_out, int out_size, void* d_ws,
                              size_t ws_size, hipStream_t stream) {
  const float* input = (const float*)d_in[0];
  const int* adj = (const int*)d_in[1];
  const float* rot = (const float*)d_in[2];
  const float* kW = (const float*)d_in[3];
  const float* vW = (const float*)d_in[4];
  float* out = (float*)d_out;

  char* ws = (char*)d_ws;

  if (ws_size >= WS_NEEDED) {
    unsigned long long* adjbits = (unsigned long long*)(ws + OFF_ABITS);
    __hip_bfloat16* vhp = (__hip_bfloat16*)(ws + OFF_VHP);
    __hip_bfloat16* khp = (__hip_bfloat16*)(ws + OFF_KHP);
    __hip_bfloat16* vhpT = (__hip_bfloat16*)(ws + OFF_VHPT);
    unsigned long long* maskbits = (unsigned long long*)(ws + OFF_MASK);
    __hip_bfloat16* S = (__hip_bfloat16*)(ws + OFF_S);
    int* perm = (int*)(ws + OFF_PERM);
    int* iperm = (int*)(ws + OFF_IPERM);
    int* buckets = (int*)(ws + OFF_BUCK);
    int* meta = (int*)(ws + OFF_META);
    float* cmean = (float*)(ws + OFF_CMEAN);
    float* rowsum = (float*)(ws + OFF_ROWI);
    __hip_bfloat16* Ab = (__hip_bfloat16*)(ws + OFF_AB);
    __hip_bfloat16* WkT = (__hip_bfloat16*)(ws + OFF_WKT);
    __hip_bfloat16* WvT = (__hip_bfloat16*)(ws + OFF_WVT);
    double* cw = (double*)(ws + OFF_CW);

    // zero khp tail rows [8192, 8320) (read masked by s_gemm pad rows) and
    // the whole vhp (pad positions must be zero for transpose/cmean).
    hipMemsetAsync(ws + OFF_KHP + (size_t)N_NODES * FEAT * 2, 0,
                   128 * FEAT * 2, stream);
    hipMemsetAsync(ws + OFF_VHP, 0, (size_t)VHPT_W * FEAT * 2, stream);
    // ---- L3-aware schedule: the 268 MB adj stream (adjbits) runs FIRST,
    // so every later producer->consumer buffer stays L3-resident.
    adjbits_kernel<<<N_NODES, 256, 0, stream>>>(adj, adjbits);
    cw_kernel<<<512, 64, 0, stream>>>(kW, rot, cw);
    rv_bucket_kernel<<<N_NODES, 64, 0, stream>>>(input, cw, buckets);
    sort_kernel<<<1, 256, 0, stream>>>(buckets, perm, iperm, meta, cmean,
                                       rowsum);
    maskpack2_kernel<<<N_NODES, 256, 0, stream>>>(adjbits, perm, meta,
                                                  maskbits);
    convert_input<<<2048, 256, 0, stream>>>(input, Ab);
    convert_w<<<dim3(8, 8, 2), 256, 0, stream>>>(kW, vW, WkT, WvT);
    mfma_dual<<<dim3(64, 4, 2), 256, 0, stream>>>(Ab, WkT, WvT, iperm, meta,
                                                  khp, vhp);
    transpose_vhpT_kernel<<<dim3(VHPT_W / 64, FEAT / 64), 256, 0, stream>>>(
        vhp, vhpT, cmean);
    s_gemm<<<dim3(2080, 1, 4), 256, 0, stream>>>(khp, meta, maskbits, S,
                                                 rowsum);
    pv_gemm<<<dim3(128, 4, 4), 256, 0, stream>>>(S, vhpT, meta, perm, cmean,
                                                 rowsum, out);
  } else {
    float* kh = (float*)(ws + 0UL);
    float* vh = (float*)(ws + 16777216UL);
    int* buckets = (int*)(ws + 33554432UL);
    dim3 gemm_grid(N_NODES / 32, FEAT / 32);
    gemm_dual<<<gemm_grid, 256, 0, stream>>>(input, kW, vW, kh, vh);
    bucket_kernel<<<N_NODES, 64, 0, stream>>>(kh, rot, buckets);
    attn_kernel<<<N_NODES, 256, 0, stream>>>(kh, vh, adj, buckets, out);
  }
}

// Round 9
// 538.286 us; speedup vs baseline: 1.0566x; 1.0566x over previous
//
#include <hip/hip_runtime.h>
#include <hip/hip_bf16.h>
#include <math.h>

#define N_NODES 8192
#define FEAT 512
#define NEGV -9e15f
#define VHPT_W 8704

typedef __attribute__((ext_vector_type(8))) short short8;
typedef __attribute__((ext_vector_type(4))) float floatx4;

// ---- workspace layout (bytes) ----
#define OFF_VHP   16777216UL   // bf16 vhp [8704][512] (padded-pos row-major)
#define OFF_KHP   33554432UL   // bf16 [8320][512]
#define OFF_VHPT  42074112UL   // bf16 [512][8704]  (padded-position columns)
#define OFF_MASK  50987008UL   // u64 [8192][128]; head reused early for cw (f64[1024])
#define OFF_S     59375616UL   // bf16 S, cap 25165824 elems; head reused early for Ab/W*T
#define OFF_PERM  109707264UL
#define OFF_BUCK  109772800UL
#define OFF_META  109805568UL  // ints: [0..4]=boff [5..8]=padded [9..13]=soff(+tot) [14..18]=poff
#define OFF_CMEAN 109806592UL
#define OFF_ROWI  109841408UL  // f32 [8192] row sum of stored P~ (exp(S), masked->0)
#define OFF_IPERM 109874176UL  // int [8192] inverse permutation
#define WS_NEEDED 109906944UL
#define CAP_S     25165824L

// aliased (early-lifetime) buffers inside the S region:
#define OFF_AB    (OFF_S)                 // bf16 [8192][512] input, bf16
#define OFF_WKT   (OFF_S + 16777216UL)    // bf16 [512][512] kW transposed
#define OFF_WVT   (OFF_S + 17825792UL)    // bf16 [512][512] vW transposed
#define OFF_CW    (OFF_MASK)              // f64 [512][2] (dead before maskpack)

static __device__ __forceinline__ unsigned short f2bf_bits(float x) {
  __hip_bfloat16 h = __float2bfloat16(x);
  unsigned short u;
  __builtin_memcpy(&u, &h, 2);
  return u;
}
static __device__ __forceinline__ float bf_bits2f(unsigned short u) {
  __hip_bfloat16 h;
  __builtin_memcpy(&h, &u, 2);
  return __bfloat162float(h);
}

// Async 16B/lane global->LDS copy (global_load_lds_dwordx4). LDS side must be
// wave-uniform base + lane*16 — all call sites below satisfy this.
static __device__ __forceinline__ void async_copy16(const void* gptr,
                                                    void* lptr) {
  __builtin_amdgcn_global_load_lds(
      (const __attribute__((address_space(1))) unsigned int*)gptr,
      (__attribute__((address_space(3))) unsigned int*)lptr, 16, 0, 0);
}

// ---------------------------------------------------------------------------
// input f32 -> bf16
// ---------------------------------------------------------------------------
__global__ __launch_bounds__(256) void convert_input(
    const float* __restrict__ A, __hip_bfloat16* __restrict__ Ab) {
  const long idx = ((long)blockIdx.x * 256 + threadIdx.x) * 8;
  const float4 v0 = *(const float4*)&A[idx];
  const float4 v1 = *(const float4*)&A[idx + 4];
  const float vv[8] = {v0.x, v0.y, v0.z, v0.w, v1.x, v1.y, v1.z, v1.w};
  union { short8 s; unsigned short u[8]; } o;
#pragma unroll
  for (int e = 0; e < 8; e++) o.u[e] = f2bf_bits(vv[e]);
  *(short8*)&Ab[idx] = o.s;
}

// ---------------------------------------------------------------------------
// W[k][n] f32 -> transposed bf16: WT[n][k]. z=0: kW, z=1: vW.
// ---------------------------------------------------------------------------
__global__ __launch_bounds__(256) void convert_w(
    const float* __restrict__ kW, const float* __restrict__ vW,
    __hip_bfloat16* __restrict__ WkT, __hip_bfloat16* __restrict__ WvT) {
  __shared__ float tile[64][65];
  const int z = blockIdx.z;
  const float* __restrict__ W = z ? vW : kW;
  __hip_bfloat16* __restrict__ T = z ? WvT : WkT;
  const int k0 = blockIdx.x * 64, n0 = blockIdx.y * 64;
  const int t = threadIdx.x;
#pragma unroll
  for (int s = 0; s < 16; s++) {
    int idx = t + s * 256;
    int r = idx >> 6, c = idx & 63;
    tile[r][c] = W[(long)(k0 + r) * FEAT + n0 + c];
  }
  __syncthreads();
#pragma unroll
  for (int s = 0; s < 16; s++) {
    int idx = t + s * 256;
    int a = idx >> 6, b = idx & 63;
    unsigned short h = f2bf_bits(tile[b][a]);
    __builtin_memcpy(&T[(long)(n0 + a) * FEAT + k0 + b], &h, 2);
  }
}

// ---------------------------------------------------------------------------
// kh/vh = A@W, plain bf16 MFMA. BK=64 dbuf, 32 MFMAs per barrier, 8 K-steps.
// Unified epilogue: acc -> Ct LDS tile -> coalesced 16B row stores, rows
// scattered to:
//   z=0: khp[iperm[r]]           (sorted order, feeds s_gemm)
//   z=1: vhp[pos(iperm[r])]      (padded-position order, feeds transpose)
// ---------------------------------------------------------------------------
__global__ __launch_bounds__(256) void mfma_dual(
    const __hip_bfloat16* __restrict__ Ab, const __hip_bfloat16* __restrict__ WkT,
    const __hip_bfloat16* __restrict__ WvT, const int* __restrict__ iperm,
    const int* __restrict__ meta, __hip_bfloat16* __restrict__ khp,
    __hip_bfloat16* __restrict__ vhp) {
  const int z = blockIdx.z;
  const __hip_bfloat16* __restrict__ WT = z ? WvT : WkT;
  const int ti = blockIdx.x, tj = blockIdx.y;
  // 64 KB union: As/Ws each [2 dbuf][2 panels][4096]; Ct[128][136] epilogue.
  __shared__ __align__(16) __hip_bfloat16 smem[32768];
  __hip_bfloat16* As = smem;            // [2][2][4096]
  __hip_bfloat16* Ws = smem + 16384;    // [2][2][4096]
  const int t = threadIdx.x;
  const int lane = t & 63, w = t >> 6;
  const int wm = (w >> 1) * 64, wn = (w & 1) * 64;
  const int quad = lane >> 4, ln = lane & 15;
  const int qr = quad * 8;
  floatx4 acc[4][4];
#pragma unroll
  for (int mi = 0; mi < 4; mi++)
#pragma unroll
    for (int ni = 0; ni < 4; ni++) acc[mi][ni] = (floatx4)0.f;

  auto STAGE = [&](int st, int buf) {
    const int k0 = st * 64;
#pragma unroll
    for (int p = 0; p < 2; p++)
#pragma unroll
      for (int s = 0; s < 2; s++) {
        int c = t + s * 256;
        int row = c >> 2, off8 = (c & 3) * 8;
        int lo = buf * 8192 + p * 4096 + row * 32 + off8;
        async_copy16(&Ab[(long)(ti * 128 + row) * FEAT + k0 + p * 32 + off8],
                     &As[lo]);
        async_copy16(&WT[(long)(tj * 128 + row) * FEAT + k0 + p * 32 + off8],
                     &Ws[lo]);
      }
  };
  STAGE(0, 0);
  __syncthreads();
  for (int st = 0; st < 8; st++) {
    const int buf = st & 1;
    if (st < 7) STAGE(st + 1, buf ^ 1);
#pragma unroll
    for (int p = 0; p < 2; p++) {
      short8 af[4], bfr[4];
#pragma unroll
      for (int mi = 0; mi < 4; mi++)
        af[mi] = *(const short8*)&As[buf * 8192 + p * 4096 +
                                     (wm + mi * 16 + ln) * 32 + qr];
#pragma unroll
      for (int ni = 0; ni < 4; ni++)
        bfr[ni] = *(const short8*)&Ws[buf * 8192 + p * 4096 +
                                      (wn + ni * 16 + ln) * 32 + qr];
#pragma unroll
      for (int mi = 0; mi < 4; mi++)
#pragma unroll
        for (int ni = 0; ni < 4; ni++)
          acc[mi][ni] = __builtin_amdgcn_mfma_f32_16x16x32_bf16(
              af[mi], bfr[ni], acc[mi][ni], 0, 0, 0);
    }
    __syncthreads();
  }
  // unified epilogue: loop-end barrier already drained LDS reads
  __hip_bfloat16* Ct = smem;  // [128][136]
#pragma unroll
  for (int mi = 0; mi < 4; mi++)
#pragma unroll
    for (int ni = 0; ni < 4; ni++) {
      int col = wn + ni * 16 + ln;
#pragma unroll
      for (int reg = 0; reg < 4; reg++) {
        int row = wm + mi * 16 + quad * 4 + reg;
        Ct[row * 136 + col] = __float2bfloat16(acc[mi][ni][reg]);
      }
    }
  __syncthreads();
  __hip_bfloat16* __restrict__ dst = z ? vhp : khp;
#pragma unroll
  for (int i = 0; i < 8; i++) {
    int idx = t + i * 256;
    int rl = idx >> 4, c8 = (idx & 15) * 8;
    int g = iperm[ti * 128 + rl];
    long drow = g;
    if (z) {
      int bb = (g >= meta[1]) + (g >= meta[2]) + (g >= meta[3]);
      drow = meta[14 + bb] + g - meta[bb];
    }
    *(short8*)&dst[drow * FEAT + tj * 128 + c8] =
        *(const short8*)&Ct[rl * 136 + c8];
  }
}

// ---------------------------------------------------------------------------
// cw[f][b] = sum_h kW[f][h] * rot[h][b]  (fp64)
// ---------------------------------------------------------------------------
__global__ __launch_bounds__(64) void cw_kernel(
    const float* __restrict__ kW, const float* __restrict__ rot,
    double* __restrict__ cw) {
  const int f = blockIdx.x;
  const int lane = threadIdx.x;
  double r0 = 0.0, r1 = 0.0;
  for (int h = lane; h < FEAT; h += 64) {
    double a = (double)kW[(long)f * FEAT + h];
    r0 += a * (double)rot[2 * h];
    r1 += a * (double)rot[2 * h + 1];
  }
#pragma unroll
  for (int off = 32; off > 0; off >>= 1) {
    r0 += __shfl_down(r0, off);
    r1 += __shfl_down(r1, off);
  }
  if (lane == 0) {
    cw[2 * f] = r0;
    cw[2 * f + 1] = r1;
  }
}

// ---------------------------------------------------------------------------
// buckets from EXACT inputs: rv = input @ cw in fp64; argmax([r0,r1,-r0,-r1])
// ---------------------------------------------------------------------------
__global__ __launch_bounds__(64) void rv_bucket_kernel(
    const float* __restrict__ input, const double* __restrict__ cw,
    int* __restrict__ buckets) {
  const int i = blockIdx.x;
  const int lane = threadIdx.x;
  double r0 = 0.0, r1 = 0.0;
  for (int f = lane; f < FEAT; f += 64) {
    double a = (double)input[(long)i * FEAT + f];
    r0 += a * cw[2 * f];
    r1 += a * cw[2 * f + 1];
  }
#pragma unroll
  for (int off = 32; off > 0; off >>= 1) {
    r0 += __shfl_down(r0, off);
    r1 += __shfl_down(r1, off);
  }
  if (lane == 0) {
    int b = 0;
    double best = r0;
    if (r1 > best)  { best = r1;  b = 1; }
    if (-r0 > best) { best = -r0; b = 2; }
    if (-r1 > best) { best = -r1; b = 3; }
    buckets[i] = b;
  }
}

// ---------------------------------------------------------------------------
// Stable counting sort by bucket (1 block, parallel Hillis-Steele scan).
// Emits perm AND inverse perm. Also zeroes cmean and rowsum.
// ---------------------------------------------------------------------------
__global__ __launch_bounds__(256) void sort_kernel(
    const int* __restrict__ buckets, int* __restrict__ perm,
    int* __restrict__ iperm, int* __restrict__ meta,
    float* __restrict__ cmean, float* __restrict__ rowsum) {
  __shared__ int lc[4][256];
  __shared__ int sc[4][256];
  __shared__ int boff_sh[5];
  const int t = threadIdx.x;
  cmean[t] = 0.f;
  cmean[t + 256] = 0.f;
  for (int k = t; k < N_NODES; k += 256) rowsum[k] = 0.f;
  const int base = t * 32;
  int c0 = 0, c1 = 0, c2 = 0, c3 = 0;
  for (int k = 0; k < 32; k++) {
    int b = buckets[base + k];
    c0 += (b == 0); c1 += (b == 1); c2 += (b == 2); c3 += (b == 3);
  }
  lc[0][t] = c0; lc[1][t] = c1; lc[2][t] = c2; lc[3][t] = c3;
  sc[0][t] = c0; sc[1][t] = c1; sc[2][t] = c2; sc[3][t] = c3;
  __syncthreads();
  for (int off = 1; off < 256; off <<= 1) {
    int a0 = (t >= off) ? sc[0][t - off] : 0;
    int a1 = (t >= off) ? sc[1][t - off] : 0;
    int a2 = (t >= off) ? sc[2][t - off] : 0;
    int a3 = (t >= off) ? sc[3][t - off] : 0;
    __syncthreads();
    sc[0][t] += a0; sc[1][t] += a1; sc[2][t] += a2; sc[3][t] += a3;
    __syncthreads();
  }
  if (t == 0) {
    int boff[5];
    boff[0] = 0;
    for (int b = 0; b < 4; b++) boff[b + 1] = boff[b] + sc[b][255];
    for (int b = 0; b < 5; b++) { meta[b] = boff[b]; boff_sh[b] = boff[b]; }
    long so = 0;
    int po = 0;
    for (int b = 0; b < 4; b++) {
      int tot = boff[b + 1] - boff[b];
      int pad = ((tot + 127) >> 7) << 7;
      meta[5 + b] = pad;
      meta[9 + b] = (int)so;
      meta[14 + b] = po;
      so += (long)pad * pad;
      po += pad;
    }
    meta[13] = (int)so;
    meta[18] = po;
    if (so > CAP_S)
      for (int b = 0; b < 4; b++) meta[5 + b] = 0;
  }
  __syncthreads();
  int s0 = boff_sh[0] + sc[0][t] - lc[0][t];
  int s1 = boff_sh[1] + sc[1][t] - lc[1][t];
  int s2 = boff_sh[2] + sc[2][t] - lc[2][t];
  int s3 = boff_sh[3] + sc[3][t] - lc[3][t];
  for (int k = 0; k < 32; k++) {
    int i = base + k;
    int b = buckets[i];
    int pos = (b == 0) ? s0++ : ((b == 1) ? s1++ : ((b == 2) ? s2++ : s3++));
    perm[pos] = i;
    iperm[i] = pos;
  }
}

// ---------------------------------------------------------------------------
// Plain bf16 transpose vhp[pos][f] -> vhpT[f][pos], fused cmean column sums.
// Pads are zero (vhp memset upfront; mfma_dual writes only real nodes).
// ---------------------------------------------------------------------------
__global__ __launch_bounds__(256) void transpose_vhpT_kernel(
    const __hip_bfloat16* __restrict__ vhp, __hip_bfloat16* __restrict__ vhpT,
    float* __restrict__ cmean) {
  __shared__ float tile[64][65];
  __shared__ float cred[4][64];
  const int g0 = blockIdx.x * 64;
  const int f0 = blockIdx.y * 64;
  const int t = threadIdx.x;
#pragma unroll
  for (int s = 0; s < 4; s++) {
    int idx = t + s * 256;              // 0..1023
    int r = idx >> 4, c4 = (idx & 15) * 4;
    ushort4 v = *(const ushort4*)&vhp[(long)(g0 + r) * FEAT + f0 + c4];
    tile[r][c4]     = bf_bits2f(v.x);
    tile[r][c4 + 1] = bf_bits2f(v.y);
    tile[r][c4 + 2] = bf_bits2f(v.z);
    tile[r][c4 + 3] = bf_bits2f(v.w);
  }
  __syncthreads();
  {
    const int c = t & 63, seg = t >> 6;
    float ps = 0.f;
#pragma unroll
    for (int rr = 0; rr < 16; rr++) ps += tile[seg * 16 + rr][c];
    cred[seg][c] = ps;
  }
  __syncthreads();
  if (t < 64)
    atomicAdd(&cmean[f0 + t],
              cred[0][t] + cred[1][t] + cred[2][t] + cred[3][t]);
#pragma unroll
  for (int s = 0; s < 2; s++) {
    int idx = t + s * 256;              // 0..511
    int fr = idx >> 3, gc8 = (idx & 7) * 8;
    union { short8 v; unsigned short u[8]; } pk;
#pragma unroll
    for (int e = 0; e < 8; e++) pk.u[e] = f2bf_bits(tile[gc8 + e][fr]);
    *(short8*)&vhpT[(long)(f0 + fr) * VHPT_W + g0 + gc8] = pk.v;
  }
}

// ---------------------------------------------------------------------------
// maskbits[g][jj] = (adj[perm[g]][perm[boff_b+jj]] > 0), bit-packed per 64.
// Fused stream (int4, 16B/lane — the split-out dword-stream variant measured
// ~25 us SLOWER, round 8) + LDS gather. Runs EARLY (right after sort): its
// 268 MB adj stream evicts L3 before any producer->consumer buffer is cached.
// ---------------------------------------------------------------------------
__global__ __launch_bounds__(256) void maskpack_kernel(
    const int* __restrict__ adj, const int* __restrict__ perm,
    const int* __restrict__ meta, unsigned long long* __restrict__ maskbits) {
  __shared__ int adj_lds[N_NODES];
  const int g = blockIdx.x;
  const int t = threadIdx.x;
  const int b = (g >= meta[1]) + (g >= meta[2]) + (g >= meta[3]);
  const int boff = meta[b];
  const int n_b = meta[b + 1] - boff;
  const int padded = meta[5 + b];
  const int i = perm[g];
  const int* arow = adj + (long)i * N_NODES;
#pragma unroll
  for (int s = 0; s < 8; s++) {
    int idx = (t + s * 256) * 4;
    *(int4*)&adj_lds[idx] = *(const int4*)&arow[idx];
  }
  __syncthreads();
  const int lane = t & 63, w = t >> 6;
  for (int jj0 = w * 64; jj0 < padded; jj0 += 256) {
    int jj = jj0 + lane;
    int pred = 0;
    if (jj < n_b) pred = adj_lds[perm[boff + jj]] > 0;
    unsigned long long mword = __ballot(pred);
    if (lane == 0) maskbits[(long)g * 128 + (jj0 >> 6)] = mword;
  }
}

// ---------------------------------------------------------------------------
// S tile = khp_b . khp_b^T (bf16 MFMA). Dbuf prefetch per 64-wide K-step.
// FUSED NO-MAX SOFTMAX NUMERATOR: epilogue stores P~ = bf16(exp(S/sqrt(H)))
// (masked -> 0) and accumulates f32 row sums via 16-lane shfl reduce + one
// atomicAdd per (row, tile). Scores bounded (~50 << 88) so f32 exp cannot
// overflow; exp(S)/sum == softmax exactly. Triangular grid ti <= tj; both
// orientations written from an LDS tile with coalesced 16B stores. Pad rows
// excluded from row-sum atomics.
// ---------------------------------------------------------------------------
__global__ __launch_bounds__(256) void s_gemm(
    const __hip_bfloat16* __restrict__ khp, const int* __restrict__ meta,
    const unsigned long long* __restrict__ maskbits,
    __hip_bfloat16* __restrict__ S, float* __restrict__ rowsum) {
  const int b = blockIdx.z;
  const int padded = meta[5 + b];
  const int T = padded >> 7;
  const int pairs = (T * (T + 1)) >> 1;
  int L = blockIdx.x;
  if (L >= pairs) return;
  int ti = 0;
  while (L >= T - ti) { L -= T - ti; ti++; }
  const int tj = ti + L;
  const int boff = meta[b];
  const int n_b = meta[b + 1] - boff;
  const long soff = meta[9 + b];
  // 64 KB: As/Bs each [2 dbuf][2 panels][4096]; Ct[128][136] epilogue.
  __shared__ __align__(16) __hip_bfloat16 smem[32768];
  __hip_bfloat16* As = smem;            // [2][2][4096]
  __hip_bfloat16* Bs = smem + 16384;    // [2][2][4096]
  const int t = threadIdx.x;
  const int lane = t & 63, w = t >> 6;
  const int wm = (w >> 1) * 64, wn = (w & 1) * 64;
  const int quad = lane >> 4, ln = lane & 15;
  const int qr = quad * 8;
  floatx4 acc[4][4];
#pragma unroll
  for (int mi = 0; mi < 4; mi++)
#pragma unroll
    for (int ni = 0; ni < 4; ni++) acc[mi][ni] = (floatx4)0.f;
  const long a_g0 = boff + ti * 128;
  const long b_g0 = boff + tj * 128;

  auto STAGE = [&](int st, int buf) {
    const int k0 = st * 64;
#pragma unroll
    for (int p = 0; p < 2; p++)
#pragma unroll
      for (int s = 0; s < 2; s++) {
        int c = t + s * 256;
        int row = c >> 2, off8 = (c & 3) * 8;
        int lo = buf * 8192 + p * 4096 + row * 32 + off8;
        async_copy16(&khp[(a_g0 + row) * FEAT + k0 + p * 32 + off8], &As[lo]);
        async_copy16(&khp[(b_g0 + row) * FEAT + k0 + p * 32 + off8], &Bs[lo]);
      }
  };
  STAGE(0, 0);
  __syncthreads();
  for (int st = 0; st < 8; st++) {
    const int buf = st & 1;
    if (st < 7) STAGE(st + 1, buf ^ 1);
#pragma unroll
    for (int p = 0; p < 2; p++) {
      short8 af[4], bfr[4];
#pragma unroll
      for (int mi = 0; mi < 4; mi++)
        af[mi] = *(const short8*)&As[buf * 8192 + p * 4096 +
                                     (wm + mi * 16 + ln) * 32 + qr];
#pragma unroll
      for (int ni = 0; ni < 4; ni++)
        bfr[ni] = *(const short8*)&Bs[buf * 8192 + p * 4096 +
                                      (wn + ni * 16 + ln) * 32 + qr];
#pragma unroll
      for (int mi = 0; mi < 4; mi++)
#pragma unroll
        for (int ni = 0; ni < 4; ni++)
          acc[mi][ni] = __builtin_amdgcn_mfma_f32_16x16x32_bf16(
              af[mi], bfr[ni], acc[mi][ni], 0, 0, 0);
    }
    __syncthreads();
  }
  // ---- epilogue: P~ = bf16(exp(acc*scale)) -> LDS tile (unmasked) ----
  const float scale = 0.04419417382415922f;  // 1/sqrt(512)
  __hip_bfloat16* Ct = smem;  // [128][136]
#pragma unroll
  for (int mi = 0; mi < 4; mi++)
#pragma unroll
    for (int ni = 0; ni < 4; ni++) {
      int col = wn + ni * 16 + ln;
#pragma unroll
      for (int reg = 0; reg < 4; reg++) {
        int row = wm + mi * 16 + quad * 4 + reg;
        Ct[row * 136 + col] =
            __float2bfloat16(__expf(acc[mi][ni][reg] * scale));
      }
    }
  __syncthreads();
  // normal orientation: coalesced 16B stores of rows of the ti-block
#pragma unroll
  for (int i = 0; i < 8; i++) {
    int idx = t + i * 256;
    int rl = idx >> 4, c8 = (idx & 15) * 8;
    int rg = ti * 128 + rl;
    int cg = tj * 128 + c8;
    union { short8 v; unsigned short u[8]; } pk;
    pk.v = *(const short8*)&Ct[rl * 136 + c8];
    unsigned long long wbits = maskbits[(long)(boff + rg) * 128 + (cg >> 6)];
    float ps = 0.f;
#pragma unroll
    for (int e = 0; e < 8; e++) {
      if (!((wbits >> ((cg & 63) + e)) & 1ULL)) pk.u[e] = 0;
      ps += bf_bits2f(pk.u[e]);
    }
    *(short8*)&S[soff + (long)rg * padded + cg] = pk.v;
    // per-row partial sum: 16 consecutive lanes share rg
#pragma unroll
    for (int off = 1; off < 16; off <<= 1) ps += __shfl_xor(ps, off);
    if (rg < n_b && (lane & 15) == 0)
      atomicAdd(&rowsum[boff + rg], ps);
  }
  // mirrored orientation (tj-block rows), skipped on diagonal
  if (ti != tj) {
#pragma unroll
    for (int i = 0; i < 8; i++) {
      int idx = t + i * 256;
      int cl = idx >> 4, r8 = (idx & 15) * 8;
      int rg = tj * 128 + cl;   // output row (column of the computed tile)
      int cg = ti * 128 + r8;   // output col base
      union { short8 v; unsigned short u[8]; } pk;
#pragma unroll
      for (int e = 0; e < 8; e++) {
        __hip_bfloat16 hv = Ct[(r8 + e) * 136 + cl];
        __builtin_memcpy(&pk.u[e], &hv, 2);
      }
      unsigned long long wbits = maskbits[(long)(boff + rg) * 128 + (cg >> 6)];
      float ps = 0.f;
#pragma unroll
      for (int e = 0; e < 8; e++) {
        if (!((wbits >> ((cg & 63) + e)) & 1ULL)) pk.u[e] = 0;
        ps += bf_bits2f(pk.u[e]);
      }
      *(short8*)&S[soff + (long)rg * padded + cg] = pk.v;
#pragma unroll
      for (int off = 1; off < 16; off <<= 1) ps += __shfl_xor(ps, off);
      if (rg < n_b && (lane & 15) == 0)
        atomicAdd(&rowsum[boff + rg], ps);
    }
  }
}

// ---------------------------------------------------------------------------
// O tile = P~ . vhp (pure bf16 GEMM), 64 rows x 128 features per block
// (round-6 shape: 528 blocks ~ 2/CU — cross-block overlap is the latency
// hider in this template; 128x128 @ 1/CU measured slower, round 7).
// Dbuf prefetch per 64-wide K-step. Epilogue: x (1/rowsum) + ELU +
// empty-row (rowsum==0) cmean fallback + scatter to out[perm[g]].
// ---------------------------------------------------------------------------
__global__ __launch_bounds__(256) void pv_gemm(
    const __hip_bfloat16* __restrict__ S, const __hip_bfloat16* __restrict__ vhpT,
    const int* __restrict__ meta, const int* __restrict__ perm,
    const float* __restrict__ cmean, const float* __restrict__ rowsum,
    float* __restrict__ out) {
  const int b = blockIdx.z;
  const int padded = meta[5 + b];
  const int ti = blockIdx.x;
  if (ti * 64 >= padded) return;
  const int boff = meta[b];
  const int n_b = meta[b + 1] - boff;
  const long soff = meta[9 + b];
  const int poff = meta[14 + b];
  const int f0 = blockIdx.y * 128;
  __shared__ __align__(16) __hip_bfloat16 As[2 * 2 * 2048];  // 16 KB
  __shared__ __align__(16) __hip_bfloat16 Bs[2 * 2 * 4096];  // 32 KB
  const int t = threadIdx.x;
  const int lane = t & 63, w = t >> 6;
  const int wm = (w >> 1) * 32, wn = (w & 1) * 64;
  const int quad = lane >> 4, ln = lane & 15;
  const int qr = quad * 8;
  floatx4 acc[2][4];
#pragma unroll
  for (int mi = 0; mi < 2; mi++)
#pragma unroll
    for (int ni = 0; ni < 4; ni++) acc[mi][ni] = (floatx4)0.f;
  const long r0 = (long)ti * 64;

  auto STAGE = [&](int st, int buf) {
    const int k0 = st * 64;
#pragma unroll
    for (int p = 0; p < 2; p++) {
      {
        int row = t >> 2, off8 = (t & 3) * 8;
        async_copy16(&S[soff + (r0 + row) * padded + k0 + p * 32 + off8],
                     &As[buf * 4096 + p * 2048 + row * 32 + off8]);
      }
#pragma unroll
      for (int s = 0; s < 2; s++) {
        int c = t + s * 256;
        int row = c >> 2, off8 = (c & 3) * 8;
        async_copy16(
            &vhpT[(long)(f0 + row) * VHPT_W + poff + k0 + p * 32 + off8],
            &Bs[buf * 8192 + p * 4096 + row * 32 + off8]);
      }
    }
  };
  const int NS = padded >> 6;
  STAGE(0, 0);
  __syncthreads();
  for (int st = 0; st < NS; st++) {
    const int buf = st & 1;
    if (st + 1 < NS) STAGE(st + 1, buf ^ 1);
#pragma unroll
    for (int p = 0; p < 2; p++) {
      short8 af[2], bfr[4];
#pragma unroll
      for (int mi = 0; mi < 2; mi++)
        af[mi] = *(const short8*)&As[buf * 4096 + p * 2048 +
                                     (wm + mi * 16 + ln) * 32 + qr];
#pragma unroll
      for (int ni = 0; ni < 4; ni++)
        bfr[ni] = *(const short8*)&Bs[buf * 8192 + p * 4096 +
                                      (wn + ni * 16 + ln) * 32 + qr];
#pragma unroll
      for (int mi = 0; mi < 2; mi++)
#pragma unroll
        for (int ni = 0; ni < 4; ni++)
          acc[mi][ni] = __builtin_amdgcn_mfma_f32_16x16x32_bf16(
              af[mi], bfr[ni], acc[mi][ni], 0, 0, 0);
    }
    __syncthreads();
  }
#pragma unroll
  for (int mi = 0; mi < 2; mi++) {
#pragma unroll
    for (int reg = 0; reg < 4; reg++) {
      int r = ti * 64 + wm + mi * 16 + quad * 4 + reg;
      if (r < n_b) {
        int g = boff + r;
        int node = perm[g];
        float rs = rowsum[g];
        int fl = (rs == 0.f);
        float inv = fl ? 0.f : 1.f / rs;
#pragma unroll
        for (int ni = 0; ni < 4; ni++) {
          int fc = f0 + wn + ni * 16 + ln;
          float v = fl ? cmean[fc] * (1.f / (float)N_NODES)
                       : acc[mi][ni][reg] * inv;
          v = v > 0.f ? v : expm1f(v);
          out[(long)node * FEAT + fc] = v;
        }
      }
    }
  }
}

// ===========================================================================
// Slow-path fallback (only if ws_size < WS_NEEDED): round-1 implementation.
// ===========================================================================
__global__ __launch_bounds__(256) void gemm_dual(
    const float* __restrict__ A, const float* __restrict__ Wk,
    const float* __restrict__ Wv, float* __restrict__ kh,
    float* __restrict__ vh) {
  __shared__ float As[32][33];
  __shared__ float Bk[32][33];
  __shared__ float Bv[32][33];
  const int tid = threadIdx.x;
  const int row0 = blockIdx.x * 32;
  const int col0 = blockIdx.y * 32;
  const int tx = tid & 15, ty = tid >> 4;
  float ck00 = 0.f, ck01 = 0.f, ck10 = 0.f, ck11 = 0.f;
  float cv00 = 0.f, cv01 = 0.f, cv10 = 0.f, cv11 = 0.f;
  for (int kt = 0; kt < FEAT; kt += 32) {
#pragma unroll
    for (int t = 0; t < 4; t++) {
      int e = tid + t * 256;
      int r = e >> 5, c = e & 31;
      As[r][c] = A[(long)(row0 + r) * FEAT + kt + c];
      Bk[r][c] = Wk[(long)(kt + r) * FEAT + col0 + c];
      Bv[r][c] = Wv[(long)(kt + r) * FEAT + col0 + c];
    }
    __syncthreads();
#pragma unroll
    for (int kk = 0; kk < 32; kk++) {
      float a0 = As[ty * 2][kk], a1 = As[ty * 2 + 1][kk];
      float bk0 = Bk[kk][tx * 2], bk1 = Bk[kk][tx * 2 + 1];
      float bv0 = Bv[kk][tx * 2], bv1 = Bv[kk][tx * 2 + 1];
      ck00 += a0 * bk0; ck01 += a0 * bk1;
      ck10 += a1 * bk0; ck11 += a1 * bk1;
      cv00 += a0 * bv0; cv01 += a0 * bv1;
      cv10 += a1 * bv0; cv11 += a1 * bv1;
    }
    __syncthreads();
  }
  const int r0 = row0 + ty * 2, c0 = col0 + tx * 2;
  kh[(long)r0 * FEAT + c0] = ck00;       kh[(long)r0 * FEAT + c0 + 1] = ck01;
  kh[(long)(r0 + 1) * FEAT + c0] = ck10; kh[(long)(r0 + 1) * FEAT + c0 + 1] = ck11;
  vh[(long)r0 * FEAT + c0] = cv00;       vh[(long)r0 * FEAT + c0 + 1] = cv01;
  vh[(long)(r0 + 1) * FEAT + c0] = cv10; vh[(long)(r0 + 1) * FEAT + c0 + 1] = cv11;
}

__global__ __launch_bounds__(64) void bucket_kernel(
    const float* __restrict__ kh, const float* __restrict__ rot,
    int* __restrict__ buckets) {
  const int i = blockIdx.x;
  const int lane = threadIdx.x;
  double r0 = 0.0, r1 = 0.0;
  for (int h = lane; h < FEAT; h += 64) {
    double a = (double)kh[(long)i * FEAT + h];
    r0 += a * (double)rot[2 * h];
    r1 += a * (double)rot[2 * h + 1];
  }
#pragma unroll
  for (int off = 32; off > 0; off >>= 1) {
    r0 += __shfl_down(r0, off);
    r1 += __shfl_down(r1, off);
  }
  if (lane == 0) {
    int b = 0;
    double best = r0;
    if (r1 > best)  { best = r1;  b = 1; }
    if (-r0 > best) { best = -r0; b = 2; }
    if (-r1 > best) { best = -r1; b = 3; }
    buckets[i] = b;
  }
}

__global__ __launch_bounds__(256) void attn_kernel(
    const float* __restrict__ kh, const float* __restrict__ vh,
    const int* __restrict__ adj, const int* __restrict__ buckets,
    float* __restrict__ out) {
  __shared__ float khi[FEAT];
  __shared__ float pbuf[N_NODES];
  __shared__ unsigned short jlist[N_NODES];
  __shared__ int cnt_sh;
  __shared__ float red[256];
  const int i = blockIdx.x;
  const int tid = threadIdx.x;
  if (tid == 0) cnt_sh = 0;
  for (int k = tid; k < FEAT; k += 256) khi[k] = kh[(long)i * FEAT + k];
  const int mybucket = buckets[i];
  __syncthreads();
  const int* adjrow = adj + (long)i * N_NODES;
  for (int j = tid; j < N_NODES; j += 256) {
    if (adjrow[j] > 0 && buckets[j] == mybucket) {
      int idx = atomicAdd(&cnt_sh, 1);
      jlist[idx] = (unsigned short)j;
    }
  }
  __syncthreads();
  const int cnt = cnt_sh;
  float mloc = -INFINITY;
  for (int idx = tid; idx < cnt; idx += 256) {
    int j = jlist[idx];
    const float4* kj = (const float4*)(kh + (long)j * FEAT);
    const float4* ki = (const float4*)khi;
    float acc = 0.f;
#pragma unroll 8
    for (int k = 0; k < FEAT / 4; k++) {
      float4 a = ki[k];
      float4 b = kj[k];
      acc += a.x * b.x + a.y * b.y + a.z * b.z + a.w * b.w;
    }
    float s = acc * 0.04419417382415922f;
    pbuf[idx] = s;
    mloc = fmaxf(mloc, s);
  }
  red[tid] = mloc;
  __syncthreads();
#pragma unroll
  for (int off = 128; off > 0; off >>= 1) {
    if (tid < off) red[tid] = fmaxf(red[tid], red[tid + off]);
    __syncthreads();
  }
  const float m = red[0];
  __syncthreads();
  float lloc = 0.f;
  for (int idx = tid; idx < cnt; idx += 256) {
    float p = expf(pbuf[idx] - m);
    pbuf[idx] = p;
    lloc += p;
  }
  red[tid] = lloc;
  __syncthreads();
#pragma unroll
  for (int off = 128; off > 0; off >>= 1) {
    if (tid < off) red[tid] += red[tid + off];
    __syncthreads();
  }
  const float l = red[0];
  __syncthreads();
  const int f = 2 * tid;
  float acc0 = 0.f, acc1 = 0.f;
  if (cnt > 0) {
#pragma unroll 4
    for (int idx = 0; idx < cnt; idx++) {
      int j = jlist[idx];
      float p = pbuf[idx];
      float2 v = *(const float2*)(vh + (long)j * FEAT + f);
      acc0 += p * v.x;
      acc1 += p * v.y;
    }
    float invl = 1.f / l;
    acc0 *= invl;
    acc1 *= invl;
  } else {
    for (int j = 0; j < N_NODES; j++) {
      float2 v = *(const float2*)(vh + (long)j * FEAT + f);
      acc0 += v.x;
      acc1 += v.y;
    }
    acc0 *= (1.f / (float)N_NODES);
    acc1 *= (1.f / (float)N_NODES);
  }
  acc0 = acc0 > 0.f ? acc0 : expm1f(acc0);
  acc1 = acc1 > 0.f ? acc1 : expm1f(acc1);
  *(float2*)(out + (long)i * FEAT + f) = make_float2(acc0, acc1);
}

extern "C" void kernel_launch(void* const* d_in, const int* in_sizes, int n_in,
                              void* d_out, int out_size, void* d_ws,
                              size_t ws_size, hipStream_t stream) {
  const float* input = (const float*)d_in[0];
  const int* adj = (const int*)d_in[1];
  const float* rot = (const float*)d_in[2];
  const float* kW = (const float*)d_in[3];
  const float* vW = (const float*)d_in[4];
  float* out = (float*)d_out;

  char* ws = (char*)d_ws;

  if (ws_size >= WS_NEEDED) {
    __hip_bfloat16* vhp = (__hip_bfloat16*)(ws + OFF_VHP);
    __hip_bfloat16* khp = (__hip_bfloat16*)(ws + OFF_KHP);
    __hip_bfloat16* vhpT = (__hip_bfloat16*)(ws + OFF_VHPT);
    unsigned long long* maskbits = (unsigned long long*)(ws + OFF_MASK);
    __hip_bfloat16* S = (__hip_bfloat16*)(ws + OFF_S);
    int* perm = (int*)(ws + OFF_PERM);
    int* iperm = (int*)(ws + OFF_IPERM);
    int* buckets = (int*)(ws + OFF_BUCK);
    int* meta = (int*)(ws + OFF_META);
    float* cmean = (float*)(ws + OFF_CMEAN);
    float* rowsum = (float*)(ws + OFF_ROWI);
    __hip_bfloat16* Ab = (__hip_bfloat16*)(ws + OFF_AB);
    __hip_bfloat16* WkT = (__hip_bfloat16*)(ws + OFF_WKT);
    __hip_bfloat16* WvT = (__hip_bfloat16*)(ws + OFF_WVT);
    double* cw = (double*)(ws + OFF_CW);

    // zero khp tail rows [8192, 8320) (read masked by s_gemm pad rows) and
    // the whole vhp (pad positions must be zero for transpose/cmean).
    hipMemsetAsync(ws + OFF_KHP + (size_t)N_NODES * FEAT * 2, 0,
                   128 * FEAT * 2, stream);
    hipMemsetAsync(ws + OFF_VHP, 0, (size_t)VHPT_W * FEAT * 2, stream);
    // ---- L3-aware schedule: the 268 MB adj stream (maskpack) runs BEFORE
    // any producer->consumer bf16 buffers are written, so khp/vhpT/S stay
    // L3-resident through the GEMM back half.
    cw_kernel<<<512, 64, 0, stream>>>(kW, rot, cw);
    rv_bucket_kernel<<<N_NODES, 64, 0, stream>>>(input, cw, buckets);
    sort_kernel<<<1, 256, 0, stream>>>(buckets, perm, iperm, meta, cmean,
                                       rowsum);
    maskpack_kernel<<<N_NODES, 256, 0, stream>>>(adj, perm, meta, maskbits);
    convert_input<<<2048, 256, 0, stream>>>(input, Ab);
    convert_w<<<dim3(8, 8, 2), 256, 0, stream>>>(kW, vW, WkT, WvT);
    mfma_dual<<<dim3(64, 4, 2), 256, 0, stream>>>(Ab, WkT, WvT, iperm, meta,
                                                  khp, vhp);
    transpose_vhpT_kernel<<<dim3(VHPT_W / 64, FEAT / 64), 256, 0, stream>>>(
        vhp, vhpT, cmean);
    s_gemm<<<dim3(2080, 1, 4), 256, 0, stream>>>(khp, meta, maskbits, S,
                                                 rowsum);
    pv_gemm<<<dim3(128, 4, 4), 256, 0, stream>>>(S, vhpT, meta, perm, cmean,
                                                 rowsum, out);
  } else {
    float* kh = (float*)(ws + 0UL);
    float* vh = (float*)(ws + 16777216UL);
    int* buckets = (int*)(ws + 33554432UL);
    dim3 gemm_grid(N_NODES / 32, FEAT / 32);
    gemm_dual<<<gemm_grid, 256, 0, stream>>>(input, kW, vW, kh, vh);
    bucket_kernel<<<N_NODES, 64, 0, stream>>>(kh, rot, buckets);
    attn_kernel<<<N_NODES, 256, 0, stream>>>(kh, vh, adj, buckets, out);
  }
}